// Round 5
// baseline (2519.110 us; speedup 1.0000x reference)
//
#include <hip/hip_runtime.h>
#include <math.h>

#define N_NODES 50000
#define N_FEAT  128
#define N_EDGES 600000
#define N_POWERS 3

#define PAIRS 5
#define EDGES_PER_BLK (64 * PAIRS)   // 320

#define CAP 81920                    // per-bucket slot capacity (mean 76728 + 20 sigma)
#define NBUCK 8

typedef _Float16 half2v __attribute__((ext_vector_type(2)));
union HU { unsigned u; half2v h; };

__device__ __forceinline__ int bucket_of(int j) { return (int)(((unsigned)j * 41u) >> 18); }

// ---- conversion: x fp32 -> packed f16 rows; block 0 also packs Wa + zeroes cursors ----
__global__ __launch_bounds__(256) void conv_x(const float* __restrict__ x,
                                              unsigned* __restrict__ xh,
                                              const float* __restrict__ Wa,
                                              unsigned* __restrict__ wah,
                                              int* __restrict__ cur) {
    const int t = blockIdx.x * 256 + threadIdx.x;   // 800000 threads exactly
    const float4* x4 = (const float4*)x;
    float4 a = x4[(size_t)t * 2];
    float4 b = x4[(size_t)t * 2 + 1];
    HU p0, p1, p2, p3;
    p0.h = half2v{(_Float16)a.x, (_Float16)a.y};
    p1.h = half2v{(_Float16)a.z, (_Float16)a.w};
    p2.h = half2v{(_Float16)b.x, (_Float16)b.y};
    p3.h = half2v{(_Float16)b.z, (_Float16)b.w};
    ((uint4*)xh)[t] = uint4{p0.u, p1.u, p2.u, p3.u};

    if (blockIdx.x == 0) {
        const int tt = threadIdx.x;
        if (tt < 192) {
            #pragma unroll
            for (int q = 0; q < 3; ++q) {
                int idx = tt + q * 192;            // 576 entries: (p,k,c)
                int c  = idx % 3;
                int pk = idx / 3;
                int k  = pk % 64;
                int p  = pk / 64;
                float w0 = Wa[p * 384 + (2 * k) * 3 + c];
                float w1 = Wa[p * 384 + (2 * k + 1) * 3 + c];
                HU u; u.h = half2v{(_Float16)w0, (_Float16)w1};
                wah[idx] = u.u;
            }
        } else if (tt < 192 + NBUCK * N_POWERS) {
            cur[tt - 192] = 0;
        }
    }
}

// ---- bucket-scatter: edges partitioned by j-slice, appended with wave-aggregated atomics ----
__global__ __launch_bounds__(256) void scatter_edges(
    const int* __restrict__ edge_index,
    int* __restrict__ sj, int* __restrict__ si, int* __restrict__ se,
    int* __restrict__ cur)
{
    const int p = blockIdx.y;
    const int e = blockIdx.x * 256 + threadIdx.x;
    const int lane = threadIdx.x & 63;
    const bool valid = e < N_EDGES;

    const int* ej = edge_index + (size_t)p * 2 * N_EDGES;
    const int* ei = ej + N_EDGES;

    int j = 0, i = 0;
    if (valid) {
        j = __builtin_nontemporal_load(ej + e);
        i = __builtin_nontemporal_load(ei + e);
    }
    const int b = valid ? bucket_of(j) : NBUCK;   // NBUCK never matches

    int pos = -1;
    #pragma unroll
    for (int bb = 0; bb < NBUCK; ++bb) {
        unsigned long long m = __ballot(b == bb);
        if (m) {
            int leader = __ffsll((long long)m) - 1;
            int base = 0;
            if (lane == leader) base = atomicAdd(&cur[p * NBUCK + bb], __popcll(m));
            base = __shfl(base, leader, 64);
            if (b == bb) pos = base + __popcll(m & ((1ull << lane) - 1ull));
        }
    }

    if (valid && pos < CAP) {
        const int slot = (p * NBUCK + b) * CAP + pos;
        sj[slot] = j;
        si[slot] = i;
        se[slot] = e;
    }
}

template<int PAT>
__device__ __forceinline__ float swz(float v) {
    return __int_as_float(__builtin_amdgcn_ds_swizzle(__float_as_int(v), PAT));
}

__device__ __forceinline__ void dot3_8(const uint4& qa0, const uint4& qa1,
                                       const uint4& qb0, const uint4& qb1,
                                       const HU wa[8][3],
                                       float& h0, float& h1, float& h2) {
    unsigned ua[8] = {qa0.x, qa0.y, qa0.z, qa0.w, qa1.x, qa1.y, qa1.z, qa1.w};
    unsigned ub[8] = {qb0.x, qb0.y, qb0.z, qb0.w, qb1.x, qb1.y, qb1.z, qb1.w};
    h0 = 0.f; h1 = 0.f; h2 = 0.f;
    #pragma unroll
    for (int k = 0; k < 8; ++k) {
        HU a, b, d;
        a.u = ua[k]; b.u = ub[k];
        d.h = a.h - b.h;
        d.u &= 0x7fff7fffu;               // packed abs
        h0 = __builtin_amdgcn_fdot2(d.h, wa[k][0].h, h0, false);
        h1 = __builtin_amdgcn_fdot2(d.h, wa[k][1].h, h1, false);
        h2 = __builtin_amdgcn_fdot2(d.h, wa[k][2].h, h2, false);
    }
}

// Main: blockIdx.x % 8 == bucket (XCD affinity); j-gathers stay in one 1.64 MB L2 slice.
__global__ __launch_bounds__(256) void adj_kernel_sorted(
    const unsigned* __restrict__ xh,
    const int* __restrict__ sj, const int* __restrict__ si, const int* __restrict__ se,
    const int* __restrict__ cur,
    const unsigned* __restrict__ wah,
    const float* __restrict__ ba,
    const float* __restrict__ Wb,
    const float* __restrict__ bb,
    float* __restrict__ out)
{
    const int p    = blockIdx.y;
    const int b    = blockIdx.x & 7;          // bucket == XCD (round-robin assumption)
    const int k    = blockIdx.x >> 3;
    const int tid  = threadIdx.x;
    const int lane = tid & 63;
    const int wave = tid >> 6;
    const int sub  = lane & 7;
    const int grp  = lane >> 3;

    const int count = cur[p * NBUCK + b];
    const int base  = k * EDGES_PER_BLK;
    if (base >= count) return;

    HU wa[8][3];
    {
        const unsigned* wp = wah + ((size_t)p * 64 + sub * 8) * 3;
        #pragma unroll
        for (int kk = 0; kk < 8; ++kk) {
            wa[kk][0].u = wp[kk * 3 + 0];
            wa[kk][1].u = wp[kk * 3 + 1];
            wa[kk][2].u = wp[kk * 3 + 2];
        }
        #pragma unroll
        for (int kk = 0; kk < 8; ++kk) {
            asm volatile("" : "+v"(wa[kk][0].u), "+v"(wa[kk][1].u), "+v"(wa[kk][2].u));
        }
    }

    const float ba0 = ba[p * 3 + 0], ba1 = ba[p * 3 + 1], ba2 = ba[p * 3 + 2];
    const float wb0 = Wb[p * 3 + 0], wb1 = Wb[p * 3 + 1], wb2 = Wb[p * 3 + 2];
    const float bbp = bb[p];

    const int slotbase = (p * NBUCK + b) * CAP;
    float* outp = out + (size_t)p * N_EDGES;

    const int eoff = wave * 8 + grp;
    const int roff = sub * 8;
    const int cm1  = count - 1;

    #pragma unroll
    for (int it = 0; it < PAIRS; ++it) {
        const int r1 = base + it * 64 + eoff;
        const int r2 = r1 + 32;
        const bool v1 = r1 < count;
        const bool v2 = r2 < count;
        const int s1 = slotbase + min(r1, cm1);   // clamp: loads stay in-bounds, stores predicated
        const int s2 = slotbase + min(r2, cm1);

        const int j1 = __builtin_nontemporal_load(sj + s1);
        const int i1 = __builtin_nontemporal_load(si + s1);
        const int j2 = __builtin_nontemporal_load(sj + s2);
        const int i2 = __builtin_nontemporal_load(si + s2);
        const int e1 = __builtin_nontemporal_load(se + s1);
        const int e2 = __builtin_nontemporal_load(se + s2);

        const uint4* rj1 = (const uint4*)(xh + ((size_t)j1 << 6) + roff);
        const uint4* ri1 = (const uint4*)(xh + ((size_t)i1 << 6) + roff);
        const uint4* rj2 = (const uint4*)(xh + ((size_t)j2 << 6) + roff);
        const uint4* ri2 = (const uint4*)(xh + ((size_t)i2 << 6) + roff);
        uint4 a0 = rj1[0], a1 = rj1[1];
        uint4 b0 = ri1[0], b1 = ri1[1];
        uint4 c0 = rj2[0], c1 = rj2[1];
        uint4 d0 = ri2[0], d1 = ri2[1];

        float h0a, h1a, h2a, h0b, h1b, h2b;
        dot3_8(a0, a1, b0, b1, wa, h0a, h1a, h2a);
        dot3_8(c0, c1, d0, d1, wa, h0b, h1b, h2b);

        h0a += swz<0x041F>(h0a); h1a += swz<0x041F>(h1a); h2a += swz<0x041F>(h2a);
        h0b += swz<0x041F>(h0b); h1b += swz<0x041F>(h1b); h2b += swz<0x041F>(h2b);
        h0a += swz<0x081F>(h0a); h1a += swz<0x081F>(h1a); h2a += swz<0x081F>(h2a);
        h0b += swz<0x081F>(h0b); h1b += swz<0x081F>(h1b); h2b += swz<0x081F>(h2b);
        h0a += swz<0x101F>(h0a); h1a += swz<0x101F>(h1a); h2a += swz<0x101F>(h2a);
        h0b += swz<0x101F>(h0b); h1b += swz<0x101F>(h1b); h2b += swz<0x101F>(h2b);

        if (sub == 0) {
            if (v1) {
                float r0 = fmaxf(h0a + ba0, 0.f);
                float r1f = fmaxf(h1a + ba1, 0.f);
                float r2f = fmaxf(h2a + ba2, 0.f);
                float s  = fmaf(r0, wb0, fmaf(r1f, wb1, fmaf(r2f, wb2, bbp)));
                __builtin_nontemporal_store(1.f / (1.f + __expf(-s)), outp + e1);
            }
            if (v2) {
                float r0 = fmaxf(h0b + ba0, 0.f);
                float r1f = fmaxf(h1b + ba1, 0.f);
                float r2f = fmaxf(h2b + ba2, 0.f);
                float s  = fmaf(r0, wb0, fmaf(r1f, wb1, fmaf(r2f, wb2, bbp)));
                __builtin_nontemporal_store(1.f / (1.f + __expf(-s)), outp + e2);
            }
        }
    }
}

// ---- round-4 path (no sorting) for mid-size ws ----
__global__ __launch_bounds__(256) void conv_x_plain(const float* __restrict__ x,
                                                    unsigned* __restrict__ xh,
                                                    const float* __restrict__ Wa,
                                                    unsigned* __restrict__ wah) {
    const int t = blockIdx.x * 256 + threadIdx.x;
    const float4* x4 = (const float4*)x;
    float4 a = x4[(size_t)t * 2];
    float4 b = x4[(size_t)t * 2 + 1];
    HU p0, p1, p2, p3;
    p0.h = half2v{(_Float16)a.x, (_Float16)a.y};
    p1.h = half2v{(_Float16)a.z, (_Float16)a.w};
    p2.h = half2v{(_Float16)b.x, (_Float16)b.y};
    p3.h = half2v{(_Float16)b.z, (_Float16)b.w};
    ((uint4*)xh)[t] = uint4{p0.u, p1.u, p2.u, p3.u};
    if (blockIdx.x == 0 && threadIdx.x < 192) {
        const int tt = threadIdx.x;
        #pragma unroll
        for (int q = 0; q < 3; ++q) {
            int idx = tt + q * 192;
            int c  = idx % 3;
            int pk = idx / 3;
            int k  = pk % 64;
            int p  = pk / 64;
            float w0 = Wa[p * 384 + (2 * k) * 3 + c];
            float w1 = Wa[p * 384 + (2 * k + 1) * 3 + c];
            HU u; u.h = half2v{(_Float16)w0, (_Float16)w1};
            wah[idx] = u.u;
        }
    }
}

__global__ __launch_bounds__(256) void adj_kernel_f16(
    const unsigned* __restrict__ xh,
    const unsigned* __restrict__ wah,
    const int*   __restrict__ edge_index,
    const float* __restrict__ ba,
    const float* __restrict__ Wb,
    const float* __restrict__ bb,
    float* __restrict__ out)
{
    const int p    = blockIdx.y;
    const int tid  = threadIdx.x;
    const int lane = tid & 63;
    const int wave = tid >> 6;
    const int sub  = lane & 7;
    const int grp  = lane >> 3;

    HU wa[8][3];
    {
        const unsigned* wp = wah + ((size_t)p * 64 + sub * 8) * 3;
        #pragma unroll
        for (int k = 0; k < 8; ++k) {
            wa[k][0].u = wp[k * 3 + 0];
            wa[k][1].u = wp[k * 3 + 1];
            wa[k][2].u = wp[k * 3 + 2];
        }
        #pragma unroll
        for (int k = 0; k < 8; ++k) {
            asm volatile("" : "+v"(wa[k][0].u), "+v"(wa[k][1].u), "+v"(wa[k][2].u));
        }
    }

    const float ba0 = ba[p * 3 + 0], ba1 = ba[p * 3 + 1], ba2 = ba[p * 3 + 2];
    const float wb0 = Wb[p * 3 + 0], wb1 = Wb[p * 3 + 1], wb2 = Wb[p * 3 + 2];
    const float bbp = bb[p];

    const int* ej = edge_index + (size_t)p * 2 * N_EDGES;
    const int* ei = ej + N_EDGES;
    float* outp = out + (size_t)p * N_EDGES;

    const int e_blk = blockIdx.x * EDGES_PER_BLK;
    const int eoff  = wave * 8 + grp;
    const int roff  = sub * 8;

    #pragma unroll
    for (int it = 0; it < PAIRS; ++it) {
        const int e1 = e_blk + it * 64 + eoff;
        const int e2 = e1 + 32;
        const int j1 = __builtin_nontemporal_load(ej + e1);
        const int i1 = __builtin_nontemporal_load(ei + e1);
        const int j2 = __builtin_nontemporal_load(ej + e2);
        const int i2 = __builtin_nontemporal_load(ei + e2);

        const uint4* rj1 = (const uint4*)(xh + ((size_t)j1 << 6) + roff);
        const uint4* ri1 = (const uint4*)(xh + ((size_t)i1 << 6) + roff);
        const uint4* rj2 = (const uint4*)(xh + ((size_t)j2 << 6) + roff);
        const uint4* ri2 = (const uint4*)(xh + ((size_t)i2 << 6) + roff);
        uint4 a0 = rj1[0], a1 = rj1[1];
        uint4 b0 = ri1[0], b1 = ri1[1];
        uint4 c0 = rj2[0], c1 = rj2[1];
        uint4 d0 = ri2[0], d1 = ri2[1];

        float h0a, h1a, h2a, h0b, h1b, h2b;
        dot3_8(a0, a1, b0, b1, wa, h0a, h1a, h2a);
        dot3_8(c0, c1, d0, d1, wa, h0b, h1b, h2b);

        h0a += swz<0x041F>(h0a); h1a += swz<0x041F>(h1a); h2a += swz<0x041F>(h2a);
        h0b += swz<0x041F>(h0b); h1b += swz<0x041F>(h1b); h2b += swz<0x041F>(h2b);
        h0a += swz<0x081F>(h0a); h1a += swz<0x081F>(h1a); h2a += swz<0x081F>(h2a);
        h0b += swz<0x081F>(h0b); h1b += swz<0x081F>(h1b); h2b += swz<0x081F>(h2b);
        h0a += swz<0x101F>(h0a); h1a += swz<0x101F>(h1a); h2a += swz<0x101F>(h2a);
        h0b += swz<0x101F>(h0b); h1b += swz<0x101F>(h1b); h2b += swz<0x101F>(h2b);

        if (sub == 0) {
            float r0 = fmaxf(h0a + ba0, 0.f);
            float r1 = fmaxf(h1a + ba1, 0.f);
            float r2 = fmaxf(h2a + ba2, 0.f);
            float s  = fmaf(r0, wb0, fmaf(r1, wb1, fmaf(r2, wb2, bbp)));
            __builtin_nontemporal_store(1.f / (1.f + __expf(-s)), outp + e1);
            r0 = fmaxf(h0b + ba0, 0.f);
            r1 = fmaxf(h1b + ba1, 0.f);
            r2 = fmaxf(h2b + ba2, 0.f);
            s  = fmaf(r0, wb0, fmaf(r1, wb1, fmaf(r2, wb2, bbp)));
            __builtin_nontemporal_store(1.f / (1.f + __expf(-s)), outp + e2);
        }
    }
}

// ---- fp32 fallback (no workspace) ----
__global__ __launch_bounds__(256) void adj_kernel_f32(
    const float* __restrict__ x,
    const int*   __restrict__ edge_index,
    const float* __restrict__ Wa,
    const float* __restrict__ ba,
    const float* __restrict__ Wb,
    const float* __restrict__ bb,
    float* __restrict__ out)
{
    const int p    = blockIdx.y;
    const int tid  = threadIdx.x;
    const int lane = tid & 63;
    const int wave = tid >> 6;
    const int sub  = lane & 15;
    const int grp  = lane >> 4;
    const int f0 = sub * 8;

    const float* Wap = Wa + (size_t)p * N_FEAT * 3;
    float wa0[8], wa1[8], wa2[8];
    #pragma unroll
    for (int k = 0; k < 8; ++k) {
        wa0[k] = Wap[(f0 + k) * 3 + 0];
        wa1[k] = Wap[(f0 + k) * 3 + 1];
        wa2[k] = Wap[(f0 + k) * 3 + 2];
    }
    const float ba0 = ba[p * 3 + 0], ba1 = ba[p * 3 + 1], ba2 = ba[p * 3 + 2];
    const float wb0 = Wb[p * 3 + 0], wb1 = Wb[p * 3 + 1], wb2 = Wb[p * 3 + 2];
    const float bbp = bb[p];

    const int e = blockIdx.x * 16 + wave * 4 + grp;
    const int* ej = edge_index + (size_t)p * 2 * N_EDGES;
    const int* ei = ej + N_EDGES;
    const int j = ej[e];
    const int i = ei[e];

    const float4* xj = (const float4*)(x + (size_t)j * N_FEAT + f0);
    const float4* xi = (const float4*)(x + (size_t)i * N_FEAT + f0);
    float4 a0 = xj[0], a1 = xj[1];
    float4 b0 = xi[0], b1 = xi[1];

    float d[8];
    d[0] = fabsf(a0.x - b0.x); d[1] = fabsf(a0.y - b0.y);
    d[2] = fabsf(a0.z - b0.z); d[3] = fabsf(a0.w - b0.w);
    d[4] = fabsf(a1.x - b1.x); d[5] = fabsf(a1.y - b1.y);
    d[6] = fabsf(a1.z - b1.z); d[7] = fabsf(a1.w - b1.w);

    float h0 = 0.f, h1 = 0.f, h2 = 0.f;
    #pragma unroll
    for (int k = 0; k < 8; ++k) {
        h0 = fmaf(d[k], wa0[k], h0);
        h1 = fmaf(d[k], wa1[k], h1);
        h2 = fmaf(d[k], wa2[k], h2);
    }
    #pragma unroll
    for (int m = 1; m < 16; m <<= 1) {
        h0 += __shfl_xor(h0, m, 64);
        h1 += __shfl_xor(h1, m, 64);
        h2 += __shfl_xor(h2, m, 64);
    }
    if (sub == 0) {
        float r0 = fmaxf(h0 + ba0, 0.f);
        float r1 = fmaxf(h1 + ba1, 0.f);
        float r2 = fmaxf(h2 + ba2, 0.f);
        float s  = fmaf(r0, wb0, fmaf(r1, wb1, fmaf(r2, wb2, bbp)));
        float w  = 1.f / (1.f + expf(-s));
        out[(size_t)p * N_EDGES + e] = w;
    }
}

extern "C" void kernel_launch(void* const* d_in, const int* in_sizes, int n_in,
                              void* d_out, int out_size, void* d_ws, size_t ws_size,
                              hipStream_t stream) {
    const float* x          = (const float*)d_in[0];
    const int*   edge_index = (const int*)d_in[1];
    const float* Wa         = (const float*)d_in[2];
    const float* ba         = (const float*)d_in[3];
    const float* Wb         = (const float*)d_in[4];
    const float* bb         = (const float*)d_in[5];
    float* out = (float*)d_out;

    const size_t x_bytes    = (size_t)N_NODES * N_FEAT * 2;                 // 12,800,000
    const size_t sort_bytes = (size_t)N_POWERS * NBUCK * CAP * 4;           // 7,864,320 each
    const size_t wa_bytes   = 2304;
    const size_t cur_bytes  = NBUCK * N_POWERS * 4;
    const size_t need_full  = x_bytes + 3 * sort_bytes + wa_bytes + cur_bytes;   // ~36.4 MB

    if (ws_size >= need_full) {
        char* w = (char*)d_ws;
        unsigned* xh  = (unsigned*)w;
        int* sj = (int*)(w + x_bytes);
        int* si = (int*)(w + x_bytes + sort_bytes);
        int* se = (int*)(w + x_bytes + 2 * sort_bytes);
        unsigned* wah = (unsigned*)(w + x_bytes + 3 * sort_bytes);
        int* cur = (int*)(w + x_bytes + 3 * sort_bytes + wa_bytes);

        conv_x<<<N_NODES * N_FEAT / 2048, 256, 0, stream>>>(x, xh, Wa, wah, cur);
        dim3 sg((N_EDGES + 255) / 256, N_POWERS);
        scatter_edges<<<sg, 256, 0, stream>>>(edge_index, sj, si, se, cur);
        dim3 grid(NBUCK * (CAP / EDGES_PER_BLK), N_POWERS);   // (2048, 3)
        adj_kernel_sorted<<<grid, 256, 0, stream>>>(xh, sj, si, se, cur, wah, ba, Wb, bb, out);
    } else if (ws_size >= x_bytes + wa_bytes) {
        unsigned* xh  = (unsigned*)d_ws;
        unsigned* wah = (unsigned*)((char*)d_ws + x_bytes);
        conv_x_plain<<<N_NODES * N_FEAT / 2048, 256, 0, stream>>>(x, xh, Wa, wah);
        dim3 grid(N_EDGES / EDGES_PER_BLK, N_POWERS);
        adj_kernel_f16<<<grid, 256, 0, stream>>>(xh, wah, edge_index, ba, Wb, bb, out);
    } else {
        dim3 grid((N_EDGES + 15) / 16, N_POWERS);
        adj_kernel_f32<<<grid, 256, 0, stream>>>(x, edge_index, Wa, ba, Wb, bb, out);
    }
}

// Round 6
// 177.133 us; speedup vs baseline: 14.2216x; 14.2216x over previous
//
#include <hip/hip_runtime.h>
#include <math.h>

#define N_NODES 50000
#define N_FEAT  128
#define N_EDGES 600000
#define N_POWERS 3

#define PAIRS 5
#define EDGES_PER_BLK (64 * PAIRS)   // 320

#define CAP 81920                    // per-bucket slot capacity
#define NBUCK 8
#define CHUNK 2048
#define NCHUNK 293                   // ceil(600000 / 2048)

typedef _Float16 half2v __attribute__((ext_vector_type(2)));
union HU { unsigned u; half2v h; };

__device__ __forceinline__ int bucket_of(int j) { return (int)(((unsigned)j * 41u) >> 18); }

// ---- conversion: x fp32 -> packed f16 rows; block 0 also packs Wa ----
__global__ __launch_bounds__(256) void conv_x_plain(const float* __restrict__ x,
                                                    unsigned* __restrict__ xh,
                                                    const float* __restrict__ Wa,
                                                    unsigned* __restrict__ wah) {
    const int t = blockIdx.x * 256 + threadIdx.x;   // 800000 threads exactly
    const float4* x4 = (const float4*)x;
    float4 a = x4[(size_t)t * 2];
    float4 b = x4[(size_t)t * 2 + 1];
    HU p0, p1, p2, p3;
    p0.h = half2v{(_Float16)a.x, (_Float16)a.y};
    p1.h = half2v{(_Float16)a.z, (_Float16)a.w};
    p2.h = half2v{(_Float16)b.x, (_Float16)b.y};
    p3.h = half2v{(_Float16)b.z, (_Float16)b.w};
    ((uint4*)xh)[t] = uint4{p0.u, p1.u, p2.u, p3.u};
    if (blockIdx.x == 0 && threadIdx.x < 192) {
        const int tt = threadIdx.x;
        #pragma unroll
        for (int q = 0; q < 3; ++q) {
            int idx = tt + q * 192;            // 576 entries: (p,k,c)
            int c  = idx % 3;
            int pk = idx / 3;
            int k  = pk % 64;
            int p  = pk / 64;
            float w0 = Wa[p * 384 + (2 * k) * 3 + c];
            float w1 = Wa[p * 384 + (2 * k + 1) * 3 + c];
            HU u; u.h = half2v{(_Float16)w0, (_Float16)w1};
            wah[idx] = u.u;
        }
    }
}

// ---- pass 1: per-chunk bucket histogram (LDS atomics only) ----
__global__ __launch_bounds__(256) void hist_kernel(const int* __restrict__ edge_index,
                                                   int* __restrict__ hist) {
    __shared__ int lh[NBUCK];
    const int p = blockIdx.y, chunk = blockIdx.x;
    if (threadIdx.x < NBUCK) lh[threadIdx.x] = 0;
    __syncthreads();
    const int* ej = edge_index + (size_t)p * 2 * N_EDGES;
    const int base = chunk * CHUNK;
    #pragma unroll
    for (int k = 0; k < 8; ++k) {
        const int e = base + k * 256 + threadIdx.x;
        if (e < N_EDGES) {
            const int j = __builtin_nontemporal_load(ej + e);
            atomicAdd(&lh[bucket_of(j)], 1);
        }
    }
    __syncthreads();
    if (threadIdx.x < NBUCK)
        hist[(p * NBUCK + threadIdx.x) * NCHUNK + chunk] = lh[threadIdx.x];
}

// ---- pass 2: exclusive scan over chunks per (p,b); 24 single-wave blocks ----
__global__ __launch_bounds__(64) void scan_hist(int* __restrict__ hist,
                                                int* __restrict__ cur) {
    const int pb = blockIdx.x;
    const int lane = threadIdx.x;
    int* h = hist + pb * NCHUNK;
    int carry = 0;
    for (int t = 0; t < NCHUNK; t += 64) {
        const int c = t + lane;
        int v = (c < NCHUNK) ? h[c] : 0;
        int s = v;
        #pragma unroll
        for (int d = 1; d < 64; d <<= 1) {
            int u = __shfl_up(s, d, 64);
            if (lane >= d) s += u;
        }
        if (c < NCHUNK) h[c] = carry + (s - v);
        carry += __shfl(s, 63, 64);
    }
    if (lane == 0) cur[pb] = carry;
}

// ---- pass 3: deterministic scatter into bucket arrays, packed u64 payload ----
__global__ __launch_bounds__(256) void scatter_pass(const int* __restrict__ edge_index,
                                                    const int* __restrict__ hist,
                                                    unsigned long long* __restrict__ su) {
    __shared__ int lc[NBUCK];
    const int p = blockIdx.y, chunk = blockIdx.x;
    if (threadIdx.x < NBUCK) lc[threadIdx.x] = 0;
    __syncthreads();
    const int* ej = edge_index + (size_t)p * 2 * N_EDGES;
    const int* ei = ej + N_EDGES;
    const int base = chunk * CHUNK;
    #pragma unroll
    for (int k = 0; k < 8; ++k) {
        const int e = base + k * 256 + threadIdx.x;
        if (e < N_EDGES) {
            const int j = __builtin_nontemporal_load(ej + e);
            const int i = __builtin_nontemporal_load(ei + e);
            const int b = bucket_of(j);
            const int pos = atomicAdd(&lc[b], 1);   // LDS atomic: rank within chunk
            const int off = hist[(p * NBUCK + b) * NCHUNK + chunk];
            const size_t slot = (size_t)(p * NBUCK + b) * CAP + off + pos;
            su[slot] = (unsigned long long)(unsigned)(j | (i << 16))
                     | ((unsigned long long)e << 32);
        }
    }
}

template<int PAT>
__device__ __forceinline__ float swz(float v) {
    return __int_as_float(__builtin_amdgcn_ds_swizzle(__float_as_int(v), PAT));
}

__device__ __forceinline__ void dot3_8(const uint4& qa0, const uint4& qa1,
                                       const uint4& qb0, const uint4& qb1,
                                       const HU wa[8][3],
                                       float& h0, float& h1, float& h2) {
    unsigned ua[8] = {qa0.x, qa0.y, qa0.z, qa0.w, qa1.x, qa1.y, qa1.z, qa1.w};
    unsigned ub[8] = {qb0.x, qb0.y, qb0.z, qb0.w, qb1.x, qb1.y, qb1.z, qb1.w};
    h0 = 0.f; h1 = 0.f; h2 = 0.f;
    #pragma unroll
    for (int k = 0; k < 8; ++k) {
        HU a, b, d;
        a.u = ua[k]; b.u = ub[k];
        d.h = a.h - b.h;
        d.u &= 0x7fff7fffu;               // packed abs
        h0 = __builtin_amdgcn_fdot2(d.h, wa[k][0].h, h0, false);
        h1 = __builtin_amdgcn_fdot2(d.h, wa[k][1].h, h1, false);
        h2 = __builtin_amdgcn_fdot2(d.h, wa[k][2].h, h2, false);
    }
}

// Main: blockIdx.x % 8 == bucket (XCD affinity); j-gathers stay in one 1.6 MB L2 slice.
__global__ __launch_bounds__(256) void adj_kernel_sorted(
    const unsigned* __restrict__ xh,
    const unsigned long long* __restrict__ su,
    const int* __restrict__ cur,
    const unsigned* __restrict__ wah,
    const float* __restrict__ ba,
    const float* __restrict__ Wb,
    const float* __restrict__ bb,
    float* __restrict__ out)
{
    const int p    = blockIdx.y;
    const int b    = blockIdx.x & 7;
    const int k    = blockIdx.x >> 3;
    const int tid  = threadIdx.x;
    const int lane = tid & 63;
    const int wave = tid >> 6;
    const int sub  = lane & 7;
    const int grp  = lane >> 3;

    const int count = cur[p * NBUCK + b];
    const int base  = k * EDGES_PER_BLK;
    if (base >= count) return;

    HU wa[8][3];
    {
        const unsigned* wp = wah + ((size_t)p * 64 + sub * 8) * 3;
        #pragma unroll
        for (int kk = 0; kk < 8; ++kk) {
            wa[kk][0].u = wp[kk * 3 + 0];
            wa[kk][1].u = wp[kk * 3 + 1];
            wa[kk][2].u = wp[kk * 3 + 2];
        }
        #pragma unroll
        for (int kk = 0; kk < 8; ++kk) {
            asm volatile("" : "+v"(wa[kk][0].u), "+v"(wa[kk][1].u), "+v"(wa[kk][2].u));
        }
    }

    const float ba0 = ba[p * 3 + 0], ba1 = ba[p * 3 + 1], ba2 = ba[p * 3 + 2];
    const float wb0 = Wb[p * 3 + 0], wb1 = Wb[p * 3 + 1], wb2 = Wb[p * 3 + 2];
    const float bbp = bb[p];

    const unsigned long long* sup = su + (size_t)(p * NBUCK + b) * CAP;
    float* outp = out + (size_t)p * N_EDGES;

    const int eoff = wave * 8 + grp;
    const int roff = sub * 8;
    const int cm1  = count - 1;

    #pragma unroll
    for (int it = 0; it < PAIRS; ++it) {
        const int r1 = base + it * 64 + eoff;
        const int r2 = r1 + 32;
        const bool v1 = r1 < count;
        const bool v2 = r2 < count;
        const int s1 = min(r1, cm1);   // clamp: loads in-bounds, stores predicated
        const int s2 = min(r2, cm1);

        const unsigned long long q1 = __builtin_nontemporal_load(sup + s1);
        const unsigned long long q2 = __builtin_nontemporal_load(sup + s2);
        const int j1 = (int)(q1 & 0xFFFFu);
        const int i1 = (int)((q1 >> 16) & 0xFFFFu);
        const int e1 = (int)(q1 >> 32);
        const int j2 = (int)(q2 & 0xFFFFu);
        const int i2 = (int)((q2 >> 16) & 0xFFFFu);
        const int e2 = (int)(q2 >> 32);

        const uint4* rj1 = (const uint4*)(xh + ((size_t)j1 << 6) + roff);
        const uint4* ri1 = (const uint4*)(xh + ((size_t)i1 << 6) + roff);
        const uint4* rj2 = (const uint4*)(xh + ((size_t)j2 << 6) + roff);
        const uint4* ri2 = (const uint4*)(xh + ((size_t)i2 << 6) + roff);
        uint4 a0 = rj1[0], a1 = rj1[1];
        uint4 b0 = ri1[0], b1 = ri1[1];
        uint4 c0 = rj2[0], c1 = rj2[1];
        uint4 d0 = ri2[0], d1 = ri2[1];

        float h0a, h1a, h2a, h0b, h1b, h2b;
        dot3_8(a0, a1, b0, b1, wa, h0a, h1a, h2a);
        dot3_8(c0, c1, d0, d1, wa, h0b, h1b, h2b);

        h0a += swz<0x041F>(h0a); h1a += swz<0x041F>(h1a); h2a += swz<0x041F>(h2a);
        h0b += swz<0x041F>(h0b); h1b += swz<0x041F>(h1b); h2b += swz<0x041F>(h2b);
        h0a += swz<0x081F>(h0a); h1a += swz<0x081F>(h1a); h2a += swz<0x081F>(h2a);
        h0b += swz<0x081F>(h0b); h1b += swz<0x081F>(h1b); h2b += swz<0x081F>(h2b);
        h0a += swz<0x101F>(h0a); h1a += swz<0x101F>(h1a); h2a += swz<0x101F>(h2a);
        h0b += swz<0x101F>(h0b); h1b += swz<0x101F>(h1b); h2b += swz<0x101F>(h2b);

        if (sub == 0) {
            if (v1) {
                float r0 = fmaxf(h0a + ba0, 0.f);
                float r1f = fmaxf(h1a + ba1, 0.f);
                float r2f = fmaxf(h2a + ba2, 0.f);
                float s  = fmaf(r0, wb0, fmaf(r1f, wb1, fmaf(r2f, wb2, bbp)));
                __builtin_nontemporal_store(1.f / (1.f + __expf(-s)), outp + e1);
            }
            if (v2) {
                float r0 = fmaxf(h0b + ba0, 0.f);
                float r1f = fmaxf(h1b + ba1, 0.f);
                float r2f = fmaxf(h2b + ba2, 0.f);
                float s  = fmaf(r0, wb0, fmaf(r1f, wb1, fmaf(r2f, wb2, bbp)));
                __builtin_nontemporal_store(1.f / (1.f + __expf(-s)), outp + e2);
            }
        }
    }
}

// ---- round-4 path (no sorting) for mid-size ws ----
__global__ __launch_bounds__(256) void adj_kernel_f16(
    const unsigned* __restrict__ xh,
    const unsigned* __restrict__ wah,
    const int*   __restrict__ edge_index,
    const float* __restrict__ ba,
    const float* __restrict__ Wb,
    const float* __restrict__ bb,
    float* __restrict__ out)
{
    const int p    = blockIdx.y;
    const int tid  = threadIdx.x;
    const int lane = tid & 63;
    const int wave = tid >> 6;
    const int sub  = lane & 7;
    const int grp  = lane >> 3;

    HU wa[8][3];
    {
        const unsigned* wp = wah + ((size_t)p * 64 + sub * 8) * 3;
        #pragma unroll
        for (int k = 0; k < 8; ++k) {
            wa[k][0].u = wp[k * 3 + 0];
            wa[k][1].u = wp[k * 3 + 1];
            wa[k][2].u = wp[k * 3 + 2];
        }
        #pragma unroll
        for (int k = 0; k < 8; ++k) {
            asm volatile("" : "+v"(wa[k][0].u), "+v"(wa[k][1].u), "+v"(wa[k][2].u));
        }
    }

    const float ba0 = ba[p * 3 + 0], ba1 = ba[p * 3 + 1], ba2 = ba[p * 3 + 2];
    const float wb0 = Wb[p * 3 + 0], wb1 = Wb[p * 3 + 1], wb2 = Wb[p * 3 + 2];
    const float bbp = bb[p];

    const int* ej = edge_index + (size_t)p * 2 * N_EDGES;
    const int* ei = ej + N_EDGES;
    float* outp = out + (size_t)p * N_EDGES;

    const int e_blk = blockIdx.x * EDGES_PER_BLK;
    const int eoff  = wave * 8 + grp;
    const int roff  = sub * 8;

    #pragma unroll
    for (int it = 0; it < PAIRS; ++it) {
        const int e1 = e_blk + it * 64 + eoff;
        const int e2 = e1 + 32;
        const int j1 = __builtin_nontemporal_load(ej + e1);
        const int i1 = __builtin_nontemporal_load(ei + e1);
        const int j2 = __builtin_nontemporal_load(ej + e2);
        const int i2 = __builtin_nontemporal_load(ei + e2);

        const uint4* rj1 = (const uint4*)(xh + ((size_t)j1 << 6) + roff);
        const uint4* ri1 = (const uint4*)(xh + ((size_t)i1 << 6) + roff);
        const uint4* rj2 = (const uint4*)(xh + ((size_t)j2 << 6) + roff);
        const uint4* ri2 = (const uint4*)(xh + ((size_t)i2 << 6) + roff);
        uint4 a0 = rj1[0], a1 = rj1[1];
        uint4 b0 = ri1[0], b1 = ri1[1];
        uint4 c0 = rj2[0], c1 = rj2[1];
        uint4 d0 = ri2[0], d1 = ri2[1];

        float h0a, h1a, h2a, h0b, h1b, h2b;
        dot3_8(a0, a1, b0, b1, wa, h0a, h1a, h2a);
        dot3_8(c0, c1, d0, d1, wa, h0b, h1b, h2b);

        h0a += swz<0x041F>(h0a); h1a += swz<0x041F>(h1a); h2a += swz<0x041F>(h2a);
        h0b += swz<0x041F>(h0b); h1b += swz<0x041F>(h1b); h2b += swz<0x041F>(h2b);
        h0a += swz<0x081F>(h0a); h1a += swz<0x081F>(h1a); h2a += swz<0x081F>(h2a);
        h0b += swz<0x081F>(h0b); h1b += swz<0x081F>(h1b); h2b += swz<0x081F>(h2b);
        h0a += swz<0x101F>(h0a); h1a += swz<0x101F>(h1a); h2a += swz<0x101F>(h2a);
        h0b += swz<0x101F>(h0b); h1b += swz<0x101F>(h1b); h2b += swz<0x101F>(h2b);

        if (sub == 0) {
            float r0 = fmaxf(h0a + ba0, 0.f);
            float r1 = fmaxf(h1a + ba1, 0.f);
            float r2 = fmaxf(h2a + ba2, 0.f);
            float s  = fmaf(r0, wb0, fmaf(r1, wb1, fmaf(r2, wb2, bbp)));
            __builtin_nontemporal_store(1.f / (1.f + __expf(-s)), outp + e1);
            r0 = fmaxf(h0b + ba0, 0.f);
            r1 = fmaxf(h1b + ba1, 0.f);
            r2 = fmaxf(h2b + ba2, 0.f);
            s  = fmaf(r0, wb0, fmaf(r1, wb1, fmaf(r2, wb2, bbp)));
            __builtin_nontemporal_store(1.f / (1.f + __expf(-s)), outp + e2);
        }
    }
}

// ---- fp32 fallback (no workspace) ----
__global__ __launch_bounds__(256) void adj_kernel_f32(
    const float* __restrict__ x,
    const int*   __restrict__ edge_index,
    const float* __restrict__ Wa,
    const float* __restrict__ ba,
    const float* __restrict__ Wb,
    const float* __restrict__ bb,
    float* __restrict__ out)
{
    const int p    = blockIdx.y;
    const int tid  = threadIdx.x;
    const int lane = tid & 63;
    const int wave = tid >> 6;
    const int sub  = lane & 15;
    const int grp  = lane >> 4;
    const int f0 = sub * 8;

    const float* Wap = Wa + (size_t)p * N_FEAT * 3;
    float wa0[8], wa1[8], wa2[8];
    #pragma unroll
    for (int k = 0; k < 8; ++k) {
        wa0[k] = Wap[(f0 + k) * 3 + 0];
        wa1[k] = Wap[(f0 + k) * 3 + 1];
        wa2[k] = Wap[(f0 + k) * 3 + 2];
    }
    const float ba0 = ba[p * 3 + 0], ba1 = ba[p * 3 + 1], ba2 = ba[p * 3 + 2];
    const float wb0 = Wb[p * 3 + 0], wb1 = Wb[p * 3 + 1], wb2 = Wb[p * 3 + 2];
    const float bbp = bb[p];

    const int e = blockIdx.x * 16 + wave * 4 + grp;
    const int* ej = edge_index + (size_t)p * 2 * N_EDGES;
    const int* ei = ej + N_EDGES;
    const int j = ej[e];
    const int i = ei[e];

    const float4* xj = (const float4*)(x + (size_t)j * N_FEAT + f0);
    const float4* xi = (const float4*)(x + (size_t)i * N_FEAT + f0);
    float4 a0 = xj[0], a1 = xj[1];
    float4 b0 = xi[0], b1 = xi[1];

    float d[8];
    d[0] = fabsf(a0.x - b0.x); d[1] = fabsf(a0.y - b0.y);
    d[2] = fabsf(a0.z - b0.z); d[3] = fabsf(a0.w - b0.w);
    d[4] = fabsf(a1.x - b1.x); d[5] = fabsf(a1.y - b1.y);
    d[6] = fabsf(a1.z - b1.z); d[7] = fabsf(a1.w - b1.w);

    float h0 = 0.f, h1 = 0.f, h2 = 0.f;
    #pragma unroll
    for (int k = 0; k < 8; ++k) {
        h0 = fmaf(d[k], wa0[k], h0);
        h1 = fmaf(d[k], wa1[k], h1);
        h2 = fmaf(d[k], wa2[k], h2);
    }
    #pragma unroll
    for (int m = 1; m < 16; m <<= 1) {
        h0 += __shfl_xor(h0, m, 64);
        h1 += __shfl_xor(h1, m, 64);
        h2 += __shfl_xor(h2, m, 64);
    }
    if (sub == 0) {
        float r0 = fmaxf(h0 + ba0, 0.f);
        float r1 = fmaxf(h1 + ba1, 0.f);
        float r2 = fmaxf(h2 + ba2, 0.f);
        float s  = fmaf(r0, wb0, fmaf(r1, wb1, fmaf(r2, wb2, bbp)));
        float w  = 1.f / (1.f + expf(-s));
        out[(size_t)p * N_EDGES + e] = w;
    }
}

extern "C" void kernel_launch(void* const* d_in, const int* in_sizes, int n_in,
                              void* d_out, int out_size, void* d_ws, size_t ws_size,
                              hipStream_t stream) {
    const float* x          = (const float*)d_in[0];
    const int*   edge_index = (const int*)d_in[1];
    const float* Wa         = (const float*)d_in[2];
    const float* ba         = (const float*)d_in[3];
    const float* Wb         = (const float*)d_in[4];
    const float* bb         = (const float*)d_in[5];
    float* out = (float*)d_out;

    const size_t x_bytes    = (size_t)N_NODES * N_FEAT * 2;                 // 12,800,000
    const size_t su_bytes   = (size_t)N_POWERS * NBUCK * CAP * 8;           // 15,728,640
    const size_t wa_bytes   = 2304;
    const size_t hist_bytes = (size_t)N_POWERS * NBUCK * NCHUNK * 4;        // 28,128
    const size_t cur_bytes  = NBUCK * N_POWERS * 4;
    const size_t need_full  = x_bytes + su_bytes + wa_bytes + hist_bytes + cur_bytes;

    if (ws_size >= need_full) {
        char* w = (char*)d_ws;
        unsigned* xh = (unsigned*)w;
        unsigned long long* su = (unsigned long long*)(w + x_bytes);
        unsigned* wah = (unsigned*)(w + x_bytes + su_bytes);
        int* hist = (int*)(w + x_bytes + su_bytes + wa_bytes);
        int* cur  = (int*)(w + x_bytes + su_bytes + wa_bytes + hist_bytes);

        conv_x_plain<<<N_NODES * N_FEAT / 2048, 256, 0, stream>>>(x, xh, Wa, wah);
        hist_kernel<<<dim3(NCHUNK, N_POWERS), 256, 0, stream>>>(edge_index, hist);
        scan_hist<<<NBUCK * N_POWERS, 64, 0, stream>>>(hist, cur);
        scatter_pass<<<dim3(NCHUNK, N_POWERS), 256, 0, stream>>>(edge_index, hist, su);
        dim3 grid(NBUCK * (CAP / EDGES_PER_BLK), N_POWERS);   // (2048, 3)
        adj_kernel_sorted<<<grid, 256, 0, stream>>>(xh, su, cur, wah, ba, Wb, bb, out);
    } else if (ws_size >= x_bytes + wa_bytes) {
        unsigned* xh  = (unsigned*)d_ws;
        unsigned* wah = (unsigned*)((char*)d_ws + x_bytes);
        conv_x_plain<<<N_NODES * N_FEAT / 2048, 256, 0, stream>>>(x, xh, Wa, wah);
        dim3 grid(N_EDGES / EDGES_PER_BLK, N_POWERS);
        adj_kernel_f16<<<grid, 256, 0, stream>>>(xh, wah, edge_index, ba, Wb, bb, out);
    } else {
        dim3 grid((N_EDGES + 15) / 16, N_POWERS);
        adj_kernel_f32<<<grid, 256, 0, stream>>>(x, edge_index, Wa, ba, Wb, bb, out);
    }
}